// Round 8
// baseline (2319.359 us; speedup 1.0000x reference)
//
#include <hip/hip_runtime.h>

#define B_ 8
#define L_ 512
#define D_ 64
#define H_ 256
#define GH 1024   // 4*H
#define EPS_ 1e-5f
#define POISON_ 0xAAAAAAAAu  // harness poisons d_ws to 0xAA bytes every launch
#define POISON64_ 0xAAAAAAAAAAAAAAAAull

typedef float f32x4 __attribute__((ext_vector_type(4)));
typedef _Float16 half8 __attribute__((ext_vector_type(8)));
typedef unsigned long long u64_;

#define MFMA16(a, b, c) __builtin_amdgcn_mfma_f32_16x16x32_f16((a), (b), (c), 0, 0, 0)
// Pin a weight fragment into the AGPR file (structural residency; builtin MFMA
// reads AGPR sources directly via its AV operand class).
#define PIN_A(x) asm volatile("" : "+a"(x))

__device__ __forceinline__ unsigned short f2h(float f) {
  _Float16 h = (_Float16)f;
  return __builtin_bit_cast(unsigned short, h);
}
__device__ __forceinline__ float h2f(unsigned short s) {
  _Float16 h = __builtin_bit_cast(_Float16, s);
  return (float)h;
}
__device__ __forceinline__ float fast_tanh(float x) {
  return 1.0f - 2.0f / (1.0f + __expf(2.0f * x));
}
__device__ __forceinline__ float fast_sig(float x) {
  return 1.0f / (1.0f + __expf(-x));
}
__device__ __forceinline__ unsigned int pack2h(float x, float y) {
  return (unsigned int)f2h(x) | ((unsigned int)f2h(y) << 16);
}
__device__ __forceinline__ unsigned int fixp(unsigned int d) { return d == POISON_ ? (d ^ 1u) : d; }
__device__ __forceinline__ u64_ fixp64(u64_ v) {
  return (u64_)fixp((unsigned int)v) | ((u64_)fixp((unsigned int)(v >> 32)) << 32);
}
__device__ __forceinline__ u64_ ldA64(const void* p) {
  return __hip_atomic_load((const u64_*)p, __ATOMIC_RELAXED, __HIP_MEMORY_SCOPE_AGENT);
}
__device__ __forceinline__ void stA64(void* p, u64_ v) {
  __hip_atomic_store((u64_*)p, v, __ATOMIC_RELAXED, __HIP_MEMORY_SCOPE_AGENT);
}
__device__ __forceinline__ void stA32(void* p, unsigned int v) {
  __hip_atomic_store((unsigned int*)p, v, __ATOMIC_RELAXED, __HIP_MEMORY_SCOPE_AGENT);
}
__device__ __forceinline__ half8 cvt8(const float* p) {
  float4 u0 = *(const float4*)p, u1 = *(const float4*)(p + 4);
  half8 t;
  t[0] = (_Float16)u0.x; t[1] = (_Float16)u0.y; t[2] = (_Float16)u0.z; t[3] = (_Float16)u0.w;
  t[4] = (_Float16)u1.x; t[5] = (_Float16)u1.y; t[6] = (_Float16)u1.z; t[7] = (_Float16)u1.w;
  return t;
}

// ---------------- K1: causal score rows (plain dot + additive) ----------------
__global__ void scores_kernel(const float* __restrict__ src,
                              float* __restrict__ Sp, float* __restrict__ Sa) {
  const int l = blockIdx.x, b = blockIdx.y;
  __shared__ float xl[D_];
  if (threadIdx.x < D_) xl[threadIdx.x] = src[(b * L_ + l) * D_ + threadIdx.x];
  __syncthreads();
  for (int m = threadIdx.x; m <= l; m += blockDim.x) {
    const float4* xr = (const float4*)&src[(b * L_ + m) * D_];
    float dp = 0.f, da = 0.f;
#pragma unroll
    for (int d4 = 0; d4 < D_ / 4; ++d4) {
      float4 v = xr[d4];
      dp += xl[d4*4+0]*v.x + xl[d4*4+1]*v.y + xl[d4*4+2]*v.z + xl[d4*4+3]*v.w;
      da += fast_tanh(xl[d4*4+0]+v.x) + fast_tanh(xl[d4*4+1]+v.y)
          + fast_tanh(xl[d4*4+2]+v.z) + fast_tanh(xl[d4*4+3]+v.w);
    }
    Sp[(b * L_ + l) * L_ + m] = dp;
    Sa[(b * L_ + l) * L_ + m] = da;
  }
}

// ---------------- K2: causal softmax + P@x ----------------
__global__ void softmax_av_kernel(const float* __restrict__ src, const float* __restrict__ Sp,
                                  const float* __restrict__ Sa, float* __restrict__ outk) {
  const int l = blockIdx.x, b = blockIdx.y, k = blockIdx.z;
  const int lane = threadIdx.x;  // 64 threads = 1 wave
  __shared__ float p[L_];
  const float* row = (k == 1) ? &Sa[(b * L_ + l) * L_] : &Sp[(b * L_ + l) * L_];
  const float scale = (k == 2) ? 0.125f : 1.0f;
  float mx = -1e30f;
  for (int m = lane; m <= l; m += 64) { float v = row[m] * scale; p[m] = v; mx = fmaxf(mx, v); }
#pragma unroll
  for (int off = 32; off > 0; off >>= 1) mx = fmaxf(mx, __shfl_xor(mx, off, 64));
  float sum = 0.f;
  for (int m = lane; m <= l; m += 64) { float e = __expf(p[m] - mx); p[m] = e; sum += e; }
#pragma unroll
  for (int off = 32; off > 0; off >>= 1) sum += __shfl_xor(sum, off, 64);
  __syncthreads();
  const float inv = 1.0f / sum;
  float acc = 0.f;
  for (int m = 0; m <= l; ++m) acc += p[m] * src[(b * L_ + m) * D_ + lane];
  outk[((k * B_ + b) * L_ + l) * D_ + lane] = acc * inv;
}

// ---------------- K3a: weighted combine ----------------
__global__ void combine_kernel(const float* __restrict__ outk, const float* __restrict__ attn_w,
                               float* __restrict__ attn) {
  int i = blockIdx.x * blockDim.x + threadIdx.x;
  if (i >= B_ * L_ * D_) return;
  int ld = i & (L_ * D_ - 1);
  float w0 = attn_w[ld], w1 = attn_w[L_ * D_ + ld], w2 = attn_w[2 * L_ * D_ + ld];
  float o0 = outk[i], o1 = outk[B_ * L_ * D_ + i], o2 = outk[2 * B_ * L_ * D_ + i];
  attn[i] = (o0 * w0 + o1 * w1 + o2 * w2) / (w0 + w1 + w2);
}

// ---------------- K3b: BatchNorm over (B,L) per feature, 3 lines ----------------
__global__ void bn1_kernel(const float* __restrict__ src, const float* __restrict__ attn,
                           const float* __restrict__ gamma, const float* __restrict__ beta,
                           float* __restrict__ line_in) {
  const int d = blockIdx.x, line = blockIdx.y;
  float s1 = 0.f, s2 = 0.f;
  for (int i = threadIdx.x; i < B_ * L_; i += blockDim.x) {
    float v = (line == 0) ? src[i * D_ + d]
            : (line == 1) ? src[i * D_ + d] + attn[i * D_ + d]
                          : attn[i * D_ + d];
    s1 += v; s2 += v * v;
  }
#pragma unroll
  for (int off = 32; off > 0; off >>= 1) { s1 += __shfl_xor(s1, off, 64); s2 += __shfl_xor(s2, off, 64); }
  __shared__ float a1[4], a2[4];
  __shared__ float mean_s, rstd_s;
  int w = threadIdx.x >> 6;
  if ((threadIdx.x & 63) == 0) { a1[w] = s1; a2[w] = s2; }
  __syncthreads();
  if (threadIdx.x == 0) {
    float t1 = a1[0] + a1[1] + a1[2] + a1[3];
    float t2 = a2[0] + a2[1] + a2[2] + a2[3];
    float mean = t1 / (float)(B_ * L_);
    float var = t2 / (float)(B_ * L_) - mean * mean;
    mean_s = mean; rstd_s = rsqrtf(var + EPS_);
  }
  __syncthreads();
  const float mean = mean_s;
  const float gs = gamma[line * D_ + d] * rstd_s, be = beta[line * D_ + d];
  for (int i = threadIdx.x; i < B_ * L_; i += blockDim.x) {
    float v = (line == 0) ? src[i * D_ + d]
            : (line == 1) ? src[i * D_ + d] + attn[i * D_ + d]
                          : attn[i * D_ + d];
    line_in[line * B_ * L_ * D_ + i * D_ + d] = (v - mean) * gs + be;
  }
}

// ---------------- K4: precompute XG0 = x·Wih0^T + bih0 + bhh0 (fp16, flip-fixed) ----
// xg layout (per line): [t][n][b] halves; line stride = 512*1024*8 = 4194304 halves.
__global__ __launch_bounds__(512) void xg0_kernel(
    const float* __restrict__ line_in, const float* __restrict__ Wih0,
    const float* __restrict__ bih0, const float* __restrict__ bhh0,
    unsigned short* __restrict__ xg0) {
  __shared__ unsigned short af[256][72];  // A stage: 256 rows (32 t x 8 b) x 64 k, pad->72
  const int tc = blockIdx.x, line = blockIdx.y;
  const int tid = threadIdx.x;
  for (int idx = tid; idx < 4096; idx += 512) {
    int row = idx >> 4, d4 = (idx & 15) * 4;
    int t = tc * 32 + (row >> 3), b = row & 7;
    float4 v = *(const float4*)&line_in[(size_t)line * (B_ * L_ * D_) + ((size_t)b * L_ + t) * D_ + d4];
    u64_ pk = (u64_)f2h(v.x) | ((u64_)f2h(v.y) << 16) | ((u64_)f2h(v.z) << 32) | ((u64_)f2h(v.w) << 48);
    *(u64_*)&af[row][d4] = pk;
  }
  __syncthreads();
  const int lane = tid & 63, w = tid >> 6, col = lane & 15, q = lane >> 4;
  unsigned short* xg_l = xg0 + (size_t)line * 4194304;
#pragma unroll 1
  for (int nt = w; nt < 64; nt += 8) {
    const int n = nt * 16 + col;
    const float* wr = &Wih0[((size_t)line * GH + n) * D_ + q * 8];
    half8 b0 = cvt8(wr), b1 = cvt8(wr + 32);
    const float bias = bih0[line * GH + n] + bhh0[line * GH + n];
#pragma unroll 1
    for (int mt = 0; mt < 16; ++mt) {
      f32x4 acc = {0.f, 0.f, 0.f, 0.f};
      half8 av0 = *(const half8*)&af[mt * 16 + col][q * 8];
      half8 av1 = *(const half8*)&af[mt * 16 + col][32 + q * 8];
      acc = MFMA16(av0, b0, acc);
      acc = MFMA16(av1, b1, acc);
      unsigned int d0 = fixp(pack2h(acc[0] + bias, acc[1] + bias));
      unsigned int d1 = fixp(pack2h(acc[2] + bias, acc[3] + bias));
      int t = tc * 32 + mt * 2 + (q >> 1);
      *(u64_*)&xg_l[(size_t)t * 8192 + n * 8 + (q & 1) * 4] = (u64_)d0 | ((u64_)d1 << 32);
    }
  }
}

// ---------------- K5: recurrence, GATE-SPLIT pair per (line,layer) ----------------
// WG GS=0 owns gates {i,f}, GS=1 owns {g,o}: 512 gate-cols x 256 k = 256 KB,
// kt0..6 in AGPRs (224 regs, "+a"-pinned), kt7 in LDS (32 KB) — round-7-verified
// residency. Per step: full-K MFMA over own cols -> gate pre-acts (acc+xg) ready
// ~0.3us into the step -> exchanged via LLC (fp16, fixp'd, self-flagging, 16-slot
// ring with consumer re-poison) -> BOTH WGs do the cell update redundantly on the
// SAME fixp'd gate values (bit-identical h, no divergence) -> full h_t lives in
// each WG's LDS: the h-exchange is gone. Store-before-poll on both sides = no
// circular wait. Two barriers/step.
template <int LAYER, int GS>
__device__ __forceinline__ void rec_core(
    const float* __restrict__ Whh_l, const unsigned short* __restrict__ xg_l,
    unsigned short* __restrict__ hseq_l,
    unsigned short* __restrict__ gb_mine, unsigned short* __restrict__ gb_peer,
    unsigned short* sm) {
  unsigned short* wlds = sm;            // kt7 frags: 32 recs x 64 lanes x 8 halves = 32 KB
  unsigned short* hb   = sm + 16384;    // [8][272] halves — full h, single buffer
  unsigned short* glds = sm + 18944;    // [4 gates][256 hid][8 b] halves = 16 KB
  const int tid = threadIdx.x, lane = tid & 63, w = tid >> 6;
  const int col = lane & 15, q = lane >> 4, qq = q & 1;
  const int arow = (col & 7) * 272;     // duplicated-batch A rows
  const int hid = tid;                  // cell assignment: 1 thread = 1 hidden unit

  // kt7 (k=224..255) weight frags -> LDS records (rec = w*8 + g2*4 + ut)
  for (int idx = tid; idx < 2048; idx += 256) {
    int rec = idx >> 6, l = idx & 63;
    int ww = rec >> 3, g2 = (rec >> 2) & 1, ut = rec & 3;
    int n = (GS * 2 + g2) * 256 + ww * 64 + ut * 16 + (l & 15);
    half8 tf = cvt8(&Whh_l[(size_t)n * H_ + 224 + (l >> 4) * 8]);
    *(half8*)&wlds[(size_t)idx * 8] = tf;
  }
  for (int i = tid; i < 2176; i += 256) hb[i] = 0;

  // kt0..6 weight frags -> AGPR file ([kt][g2][ut], 56 frags = 224 regs)
  f32x4 wf[7][2][4];
#pragma unroll
  for (int g2 = 0; g2 < 2; ++g2)
#pragma unroll
    for (int ut = 0; ut < 4; ++ut) {
      const float* wr = &Whh_l[(size_t)((GS * 2 + g2) * 256 + w * 64 + ut * 16 + col) * H_ + q * 8];
#pragma unroll
      for (int kt = 0; kt < 7; ++kt) {
        wf[kt][g2][ut] = __builtin_bit_cast(f32x4, cvt8(wr + kt * 32));
        PIN_A(wf[kt][g2][ut]);
      }
      __builtin_amdgcn_sched_barrier(0);  // cap in-flight prologue loads
    }

  float c_[8] = {0.f, 0.f, 0.f, 0.f, 0.f, 0.f, 0.f, 0.f};
  __syncthreads();

#pragma unroll 1
  for (int t = 0; t < L_; ++t) {
    // re-pin: weights must be AGPR-resident at every iteration boundary
#pragma unroll
    for (int kt = 0; kt < 7; ++kt)
#pragma unroll
      for (int g2 = 0; g2 < 2; ++g2) {
        PIN_A(wf[kt][g2][0]); PIN_A(wf[kt][g2][1]);
        PIN_A(wf[kt][g2][2]); PIN_A(wf[kt][g2][3]);
      }

    const int slot = t & 15;
    unsigned short* gm = gb_mine + slot * 4096;
    unsigned short* gp = gb_peer + slot * 4096;

    // xg loads for own cols, issued up front (q>=2 lanes mirror q&1 — same data)
    u64_ xv[2][4];
    const unsigned short* xt = xg_l + (size_t)t * 8192 + qq * 4;
#pragma unroll
    for (int g2 = 0; g2 < 2; ++g2)
#pragma unroll
      for (int ut = 0; ut < 4; ++ut) {
        const unsigned short* a = xt + ((GS * 2 + g2) * 256 + w * 64 + ut * 16 + col) * 8;
        xv[g2][ut] = LAYER ? ldA64(a) : *(const u64_*)a;
      }

    // full-K MFMA over own 512 gate-cols (h complete in LDS — no mid-step wait)
    f32x4 acc[2][4] = {{{0.f,0.f,0.f,0.f},{0.f,0.f,0.f,0.f},{0.f,0.f,0.f,0.f},{0.f,0.f,0.f,0.f}},
                       {{0.f,0.f,0.f,0.f},{0.f,0.f,0.f,0.f},{0.f,0.f,0.f,0.f},{0.f,0.f,0.f,0.f}}};
#pragma unroll
    for (int kt = 0; kt < 7; ++kt) {
      half8 av = *(const half8*)&hb[arow + kt * 32 + q * 8];
#pragma unroll
      for (int g2 = 0; g2 < 2; ++g2) {
        acc[g2][0] = MFMA16(av, __builtin_bit_cast(half8, wf[kt][g2][0]), acc[g2][0]);
        acc[g2][1] = MFMA16(av, __builtin_bit_cast(half8, wf[kt][g2][1]), acc[g2][1]);
        acc[g2][2] = MFMA16(av, __builtin_bit_cast(half8, wf[kt][g2][2]), acc[g2][2]);
        acc[g2][3] = MFMA16(av, __builtin_bit_cast(half8, wf[kt][g2][3]), acc[g2][3]);
      }
    }
    {
      half8 av7 = *(const half8*)&hb[arow + 224 + q * 8];
#pragma unroll
      for (int g2 = 0; g2 < 2; ++g2) {
        acc[g2][0] = MFMA16(av7, *(const half8*)&wlds[(size_t)((w * 8 + g2 * 4 + 0) * 64 + lane) * 8], acc[g2][0]);
        acc[g2][1] = MFMA16(av7, *(const half8*)&wlds[(size_t)((w * 8 + g2 * 4 + 1) * 64 + lane) * 8], acc[g2][1]);
        acc[g2][2] = MFMA16(av7, *(const half8*)&wlds[(size_t)((w * 8 + g2 * 4 + 2) * 64 + lane) * 8], acc[g2][2]);
        acc[g2][3] = MFMA16(av7, *(const half8*)&wlds[(size_t)((w * 8 + g2 * 4 + 3) * 64 + lane) * 8], acc[g2][3]);
      }
    }

    // layer-1: wait for xg (steady state passes first check)
    if (LAYER) {
      for (;;) {
        bool bad = false;
#pragma unroll
        for (int g2 = 0; g2 < 2; ++g2)
#pragma unroll
          for (int ut = 0; ut < 4; ++ut)
            bad = bad | ((unsigned int)xv[g2][ut] == POISON_) |
                        ((unsigned int)(xv[g2][ut] >> 32) == POISON_);
        if (!bad) break;
        __builtin_amdgcn_s_sleep(2);
#pragma unroll
        for (int g2 = 0; g2 < 2; ++g2)
#pragma unroll
          for (int ut = 0; ut < 4; ++ut)
            xv[g2][ut] = ldA64(xt + ((GS * 2 + g2) * 256 + w * 64 + ut * 16 + col) * 8);
      }
    }

    // extract gate pre-acts (acc + xg), fixp, store to LLC + own glds region.
    // D-layout: lane q<2 holds batches q*4..q*4+3 for col; q>=2 rows are dups.
    if (q < 2) {
#pragma unroll
      for (int g2 = 0; g2 < 2; ++g2)
#pragma unroll
        for (int ut = 0; ut < 4; ++ut) {
          f32x4 A = acc[g2][ut];
          u64_ x = xv[g2][ut];
          float v0 = A[0] + h2f((unsigned short)x);
          float v1 = A[1] + h2f((unsigned short)(x >> 16));
          float v2 = A[2] + h2f((unsigned short)(x >> 32));
          float v3 = A[3] + h2f((unsigned short)(x >> 48));
          u64_ pk = fixp64((u64_)pack2h(v0, v1) | ((u64_)pack2h(v2, v3) << 32));
          const int off = (g2 * 256 + w * 64 + ut * 16 + col) * 8 + q * 4;
          stA64(&gm[off], pk);                       // exchange (self-flagging)
          *(u64_*)&glds[GS * 2 * 2048 + off] = pk;   // own staging (same fixp'd value!)
        }
    }

    // poll partner's 8 KB (4 u64/thread, round-based bare spin) -> stage -> re-poison
    {
      const u64_* pp = (const u64_*)gp + tid * 4;
      u64_ v0, v1, v2, v3;
      for (;;) {
        v0 = ldA64(pp + 0); v1 = ldA64(pp + 1); v2 = ldA64(pp + 2); v3 = ldA64(pp + 3);
        bool bad = ((unsigned int)v0 == POISON_) | ((unsigned int)(v0 >> 32) == POISON_)
                 | ((unsigned int)v1 == POISON_) | ((unsigned int)(v1 >> 32) == POISON_)
                 | ((unsigned int)v2 == POISON_) | ((unsigned int)(v2 >> 32) == POISON_)
                 | ((unsigned int)v3 == POISON_) | ((unsigned int)(v3 >> 32) == POISON_);
        if (!bad) break;
      }
      u64_* d = (u64_*)&glds[(GS ^ 1) * 2 * 2048] + tid * 4;
      d[0] = v0; d[1] = v1; d[2] = v2; d[3] = v3;
      // re-poison for reuse at t+16 (16-step pacing guarantees drain order)
      stA64((void*)(pp + 0), POISON64_); stA64((void*)(pp + 1), POISON64_);
      stA64((void*)(pp + 2), POISON64_); stA64((void*)(pp + 3), POISON64_);
    }
    __syncthreads();  // B_mid: gates staged; all MFMA h-reads complete

    // redundant cell update: thread hid, all 8 batches (gate order i,f,g,o)
    half8 gi8 = *(const half8*)&glds[0 * 2048 + hid * 8];
    half8 gf8 = *(const half8*)&glds[1 * 2048 + hid * 8];
    half8 gg8 = *(const half8*)&glds[2 * 2048 + hid * 8];
    half8 go8 = *(const half8*)&glds[3 * 2048 + hid * 8];
    unsigned short hh[8];
#pragma unroll
    for (int b = 0; b < 8; ++b) {
      float i_ = fast_sig((float)gi8[b]);
      float f_ = fast_sig((float)gf8[b]);
      float g_ = fast_tanh((float)gg8[b]);
      float o_ = fast_sig((float)go8[b]);
      float cv = f_ * c_[b] + i_ * g_;
      c_[b] = cv;
      float hv = o_ * fast_tanh(cv);
      hh[b] = f2h(hv);
      hb[b * 272 + hid] = hh[b];
    }

    // hseq store (GS0 only): pack hid pairs via lane shuffle, self-flagging u32
    unsigned int m01 = (unsigned)hh[0] | ((unsigned)hh[1] << 16);
    unsigned int m23 = (unsigned)hh[2] | ((unsigned)hh[3] << 16);
    unsigned int m45 = (unsigned)hh[4] | ((unsigned)hh[5] << 16);
    unsigned int m67 = (unsigned)hh[6] | ((unsigned)hh[7] << 16);
    unsigned int t01 = __shfl_xor(m01, 1, 64), t23 = __shfl_xor(m23, 1, 64);
    unsigned int t45 = __shfl_xor(m45, 1, 64), t67 = __shfl_xor(m67, 1, 64);
    if (GS == 0) {
      unsigned short* hs = &hseq_l[(size_t)t * 2048];
      if ((hid & 1) == 0) {  // columns (hid, hid+1), batches 0..3
        stA32(&hs[0 * 256 + hid], fixp((m01 & 0xFFFFu) | (t01 << 16)));
        stA32(&hs[1 * 256 + hid], fixp((m01 >> 16) | (t01 & 0xFFFF0000u)));
        stA32(&hs[2 * 256 + hid], fixp((m23 & 0xFFFFu) | (t23 << 16)));
        stA32(&hs[3 * 256 + hid], fixp((m23 >> 16) | (t23 & 0xFFFF0000u)));
      } else {               // columns (hid-1, hid), batches 4..7
        stA32(&hs[4 * 256 + hid - 1], fixp((t45 & 0xFFFFu) | (m45 << 16)));
        stA32(&hs[5 * 256 + hid - 1], fixp((t45 >> 16) | (m45 & 0xFFFF0000u)));
        stA32(&hs[6 * 256 + hid - 1], fixp((t67 & 0xFFFFu) | (m67 << 16)));
        stA32(&hs[7 * 256 + hid - 1], fixp((t67 >> 16) | (m67 & 0xFFFF0000u)));
      }
    }
    __syncthreads();  // B1: h_t in LDS for next step's MFMA
  }
}

// Streaming GEMM (4 waves): XG1 = hseq0·Wih1^T + bias, 4-timestep chunks.
__device__ __forceinline__ void gemm1_core(
    const unsigned short* __restrict__ hs0_l, const float* __restrict__ Wih_l,
    const float* __restrict__ bih_l, const float* __restrict__ bhh_l,
    unsigned short* __restrict__ xg_l, int nq, unsigned short* sm) {
  unsigned short* wlds = sm;          // 128 records (nt*8+kt) x 64 lanes x 8 halves
  unsigned short* as_ = sm + 65536;   // A stage [32][264] halves
  const int tid = threadIdx.x, lane = tid & 63, w = tid >> 6;
  const int col = lane & 15, q = lane >> 4;

  for (int idx = tid; idx < 8192; idx += 256) {
    int rec = idx >> 6, l = idx & 63;
    int nt = rec >> 3, kt = rec & 7;
    int n = nq * 256 + nt * 16 + (l & 15);
    half8 tf = cvt8(&Wih_l[(size_t)n * H_ + kt * 32 + (l >> 4) * 8]);
    *(half8*)&wlds[(size_t)idx * 8] = tf;
  }
  float biasr[4];
#pragma unroll
  for (int i = 0; i < 4; ++i) {
    int n = nq * 256 + (w * 4 + i) * 16 + col;
    biasr[i] = bih_l[n] + bhh_l[n];
  }
  __syncthreads();

#pragma unroll 1
  for (int c = 0; c < 128; ++c) {
    // round-based poll of the 16 KB chunk (4 t x 8 b x 256 h fp16), reg-staged
    const u64_* srcp = (const u64_*)&hs0_l[(size_t)c * 8192] + tid;
    u64_ v[8];
    for (;;) {
#pragma unroll
      for (int r = 0; r < 8; ++r) v[r] = ldA64(srcp + r * 256);
      bool bad = false;
#pragma unroll
      for (int r = 0; r < 8; ++r)
        bad = bad | ((unsigned int)v[r] == POISON_) | ((unsigned int)(v[r] >> 32) == POISON_);
      if (!bad) break;
      __builtin_amdgcn_s_sleep(16);  // throttle: producer takes ~4 steps/chunk
    }
    __syncthreads();  // WAR: previous chunk's a-frag reads done
#pragma unroll
    for (int r = 0; r < 8; ++r)
      *(u64_*)&as_[(size_t)(w + r * 4) * 264 + lane * 4] = v[r];
    __syncthreads();

    const int t0 = c * 4;
#pragma unroll
    for (int mt = 0; mt < 2; ++mt) {
      f32x4 a0 = {0.f,0.f,0.f,0.f}, a1 = a0, a2 = a0, a3 = a0;
#pragma unroll
      for (int kt = 0; kt < 8; ++kt) {
        half8 af = *(const half8*)&as_[(size_t)(mt * 16 + col) * 264 + kt * 32 + q * 8];
        a0 = MFMA16(af, *(const half8*)&wlds[(size_t)(((w * 4 + 0) * 8 + kt) * 64 + lane) * 8], a0);
        a1 = MFMA16(af, *(const half8*)&wlds[(size_t)(((w * 4 + 1) * 8 + kt) * 64 + lane) * 8], a1);
        a2 = MFMA16(af, *(const half8*)&wlds[(size_t)(((w * 4 + 2) * 8 + kt) * 64 + lane) * 8], a2);
        a3 = MFMA16(af, *(const half8*)&wlds[(size_t)(((w * 4 + 3) * 8 + kt) * 64 + lane) * 8], a3);
      }
      const int t = t0 + mt * 2 + (q >> 1);
#pragma unroll
      for (int i = 0; i < 4; ++i) {
        const f32x4 A = (i == 0) ? a0 : (i == 1) ? a1 : (i == 2) ? a2 : a3;
        const int n = nq * 256 + (w * 4 + i) * 16 + col;
        unsigned int d0 = fixp(pack2h(A[0] + biasr[i], A[1] + biasr[i]));
        unsigned int d1 = fixp(pack2h(A[2] + biasr[i], A[3] + biasr[i]));
        stA64(&xg_l[(size_t)t * 8192 + n * 8 + (q & 1) * 4], (u64_)d0 | ((u64_)d1 << 32));
      }
    }
  }
}

__global__ __launch_bounds__(256, 1) void rec2_kernel(
    const float* __restrict__ Whh0, const float* __restrict__ Whh1,
    const float* __restrict__ Wih1, const float* __restrict__ bih1,
    const float* __restrict__ bhh1,
    const unsigned short* __restrict__ xg0, unsigned short* __restrict__ xg1,
    unsigned short* __restrict__ hseq0, unsigned short* __restrict__ hseq1,
    unsigned short* __restrict__ gbuf) {
  extern __shared__ unsigned short sm[];
  const int blk = blockIdx.x;
  if (blk < 12) {
    const int ll = blk >> 1, gs = blk & 1;
    const int line = ll % 3, layer = ll / 3;
    unsigned short* gbase = gbuf + (size_t)ll * 131072;  // 2 dirs x 16 slots x 4096 halves
    unsigned short* gmine = gbase + gs * 65536;
    unsigned short* gpeer = gbase + (gs ^ 1) * 65536;
    if (layer == 0) {
      const float* W = Whh0 + (size_t)line * GH * H_;
      const unsigned short* X = xg0 + (size_t)line * 4194304;
      unsigned short* S = hseq0 + (size_t)line * (L_ * B_ * H_);
      if (gs == 0) rec_core<0, 0>(W, X, S, gmine, gpeer, sm);
      else         rec_core<0, 1>(W, X, S, gmine, gpeer, sm);
    } else {
      const float* W = Whh1 + (size_t)line * GH * H_;
      const unsigned short* X = xg1 + (size_t)line * 4194304;
      unsigned short* S = hseq1 + (size_t)line * (L_ * B_ * H_);
      if (gs == 0) rec_core<1, 0>(W, X, S, gmine, gpeer, sm);
      else         rec_core<1, 1>(W, X, S, gmine, gpeer, sm);
    }
  } else {
    const int g = blk - 12, line = g % 3, nq = g / 3;
    gemm1_core(hseq0 + (size_t)line * (L_ * B_ * H_), Wih1 + (size_t)line * GH * H_,
               bih1 + (size_t)line * GH, bhh1 + (size_t)line * GH,
               xg1 + (size_t)line * 4194304, nq, sm);
  }
}

// ---------------- K6a: bn2 statistics over weighted cat ----------------
__global__ void bn2stats_kernel(const unsigned short* __restrict__ hseq1,
                                const float* __restrict__ cat_w, float* __restrict__ stats) {
  const int h = blockIdx.x;
  float s1 = 0.f, s2 = 0.f;
  for (int i = threadIdx.x; i < B_ * L_; i += blockDim.x) {
    int l = i >> 3, b = i & 7;
    float w0 = cat_w[(0 * L_ + l) * H_ + h], w1 = cat_w[(1 * L_ + l) * H_ + h],
          w2 = cat_w[(2 * L_ + l) * H_ + h];
    float v0 = h2f(hseq1[((0 * L_ + l) * B_ + b) * H_ + h]);
    float v1 = h2f(hseq1[((1 * L_ + l) * B_ + b) * H_ + h]);
    float v2 = h2f(hseq1[((2 * L_ + l) * B_ + b) * H_ + h]);
    float v = (v0 * w0 + v1 * w1 + v2 * w2) / (w0 + w1 + w2);
    s1 += v; s2 += v * v;
  }
#pragma unroll
  for (int off = 32; off > 0; off >>= 1) { s1 += __shfl_xor(s1, off, 64); s2 += __shfl_xor(s2, off, 64); }
  __shared__ float a1[4], a2[4];
  int w = threadIdx.x >> 6;
  if ((threadIdx.x & 63) == 0) { a1[w] = s1; a2[w] = s2; }
  __syncthreads();
  if (threadIdx.x == 0) {
    float t1 = a1[0] + a1[1] + a1[2] + a1[3];
    float t2 = a2[0] + a2[1] + a2[2] + a2[3];
    float mean = t1 / (float)(B_ * L_);
    float var = t2 / (float)(B_ * L_) - mean * mean;
    stats[2 * h] = mean;
    stats[2 * h + 1] = rsqrtf(var + EPS_);
  }
}

// ---------------- K6b: normalize last timestep + FC ----------------
__global__ void final_kernel(const unsigned short* __restrict__ hseq1,
                             const float* __restrict__ cat_w, const float* __restrict__ stats,
                             const float* __restrict__ gamma, const float* __restrict__ beta,
                             const float* __restrict__ fcW, const float* __restrict__ fcb,
                             float* __restrict__ out) {
  const int h = threadIdx.x;  // 256
  __shared__ float vmat[B_][H_];
  const float mean = stats[2 * h], rstd = stats[2 * h + 1];
  const float g = gamma[h], be = beta[h];
  const int l = L_ - 1;
  float w0 = cat_w[(0 * L_ + l) * H_ + h], w1 = cat_w[(1 * L_ + l) * H_ + h],
        w2 = cat_w[(2 * L_ + l) * H_ + h];
  const float wsum = w0 + w1 + w2;
  for (int b = 0; b < B_; ++b) {
    float v0 = h2f(hseq1[((0 * L_ + l) * B_ + b) * H_ + h]);
    float v1 = h2f(hseq1[((1 * L_ + l) * B_ + b) * H_ + h]);
    float v2 = h2f(hseq1[((2 * L_ + l) * B_ + b) * H_ + h]);
    float v = (v0 * w0 + v1 * w1 + v2 * w2) / wsum;
    vmat[b][h] = (v - mean) * rstd * g + be;
  }
  __syncthreads();
  if (h < 64) {
    int b = h >> 3, c = h & 7;
    float acc = fcb[c];
    for (int k = 0; k < H_; ++k) acc += vmat[b][k] * fcW[c * H_ + k];
    out[b * 8 + c] = acc;
  }
}

extern "C" void kernel_launch(void* const* d_in, const int* in_sizes, int n_in,
                              void* d_out, int out_size, void* d_ws, size_t ws_size,
                              hipStream_t stream) {
  (void)in_sizes; (void)n_in; (void)out_size; (void)ws_size;
  const float* src       = (const float*)d_in[0];
  const float* attn_w    = (const float*)d_in[1];
  const float* cat_w     = (const float*)d_in[2];
  const float* bn1_gamma = (const float*)d_in[3];
  const float* bn1_beta  = (const float*)d_in[4];
  const float* bn2_gamma = (const float*)d_in[5];
  const float* bn2_beta  = (const float*)d_in[6];
  const float* Wih0      = (const float*)d_in[7];
  const float* Whh0      = (const float*)d_in[8];
  const float* bih0      = (const float*)d_in[9];
  const float* bhh0      = (const float*)d_in[10];
  const float* Wih1      = (const float*)d_in[11];
  const float* Whh1      = (const float*)d_in[12];
  const float* bih1      = (const float*)d_in[13];
  const float* bhh1      = (const float*)d_in[14];
  const float* fcW       = (const float*)d_in[15];
  const float* fcb       = (const float*)d_in[16];
  float* out = (float*)d_out;

  char* p = (char*)d_ws;
  float* Sp = (float*)p;                      p += (size_t)B_ * L_ * L_ * 4;
  float* Sa = (float*)p;                      p += (size_t)B_ * L_ * L_ * 4;
  float* outk = (float*)p;                    p += (size_t)3 * B_ * L_ * D_ * 4;
  float* attn = (float*)p;                    p += (size_t)B_ * L_ * D_ * 4;
  float* line_in = (float*)p;                 p += (size_t)3 * B_ * L_ * D_ * 4;
  float* stats = (float*)p;                   p += (size_t)512 * 4;
  unsigned short* hseq0 = (unsigned short*)p; p += (size_t)3 * L_ * B_ * H_ * 2;
  unsigned short* hseq1 = (unsigned short*)p; p += (size_t)3 * L_ * B_ * H_ * 2;
  unsigned short* xg0 = (unsigned short*)p;   p += (size_t)3 * L_ * GH * B_ * 2;
  unsigned short* xg1 = (unsigned short*)p;   p += (size_t)3 * L_ * GH * B_ * 2;
  unsigned short* gbuf = (unsigned short*)p;  p += (size_t)6 * 2 * 16 * 8192;  // 1.5 MB

  scores_kernel<<<dim3(L_, B_), dim3(256), 0, stream>>>(src, Sp, Sa);
  softmax_av_kernel<<<dim3(L_, B_, 3), dim3(64), 0, stream>>>(src, Sp, Sa, outk);
  combine_kernel<<<dim3((B_ * L_ * D_) / 256), dim3(256), 0, stream>>>(outk, attn_w, attn);
  bn1_kernel<<<dim3(D_, 3), dim3(256), 0, stream>>>(src, attn, bn1_gamma, bn1_beta, line_in);
  xg0_kernel<<<dim3(16, 3), dim3(512), 0, stream>>>(line_in, Wih0, bih0, bhh0, xg0);
  rec2_kernel<<<dim3(24), dim3(256), 147968, stream>>>(
      Whh0, Whh1, Wih1, bih1, bhh1, xg0, xg1, hseq0, hseq1, gbuf);
  bn2stats_kernel<<<dim3(H_), dim3(256), 0, stream>>>(hseq1, cat_w, stats);
  final_kernel<<<dim3(1), dim3(256), 0, stream>>>(hseq1, cat_w, stats, bn2_gamma, bn2_beta,
                                                  fcW, fcb, out);
}